// Round 12
// baseline (168.027 us; speedup 1.0000x reference)
//
#include <hip/hip_runtime.h>
#include <math.h>

#define D_MODEL 1024
#define N_HEADS 16
#define HEAD_DIM 64
#define BATCH 2
#define SEQ 2048
#define WIN_L 127
#define WIN_R 128

typedef float f32x4 __attribute__((ext_vector_type(4)));
typedef __bf16 bf16x8 __attribute__((ext_vector_type(8)));
typedef unsigned short ushort8_t __attribute__((ext_vector_type(8)));

typedef const __attribute__((address_space(1))) void* gptr_t;
typedef __attribute__((address_space(3))) void* lptr_t;

__device__ __forceinline__ unsigned short f2bf(float v) {
    unsigned u = __float_as_uint(v);
    unsigned r = (u + 0x7FFF + ((u >> 16) & 1)) >> 16;   // RNE
    return (unsigned short)r;
}

// ---------------------------------------------------------------------------
// fp32 -> bf16 for all three inputs in one launch.
// ---------------------------------------------------------------------------
#define NX_ELEM (4096 * 1024)
#define NW_ELEM (3072 * 1024)
#define NO_ELEM (1024 * 1024)

__global__ __launch_bounds__(256)
void cvt_all(const float* __restrict__ x, const float* __restrict__ wq,
             const float* __restrict__ wo, unsigned short* __restrict__ xb,
             unsigned short* __restrict__ wqb, unsigned short* __restrict__ wob)
{
    int i = (blockIdx.x * 256 + threadIdx.x) * 4;
    const float* src;
    unsigned short* dst;
    int off;
    if (i < NX_ELEM)                 { src = x;  dst = xb;  off = i; }
    else if (i < NX_ELEM + NW_ELEM)  { src = wq; dst = wqb; off = i - NX_ELEM; }
    else                             { src = wo; dst = wob; off = i - NX_ELEM - NW_ELEM; }
    float4 f = *(const float4*)(src + off);
    ushort4 o;
    o.x = f2bf(f.x); o.y = f2bf(f.y); o.z = f2bf(f.z); o.w = f2bf(f.w);
    *(ushort4*)(dst + off) = o;
}

// ---------------------------------------------------------------------------
// QKV GEMM (NT) with fused RoPE + layout epilogue.  (R9-proven config)
// BK=64 per barrier as two BK=32 panels; (256,3) -> 3 blocks/CU.
// ---------------------------------------------------------------------------
__global__ __launch_bounds__(256, 3)
void gemm_qkv(const unsigned short* __restrict__ A,
              const unsigned short* __restrict__ B,
              unsigned short* __restrict__ qb,
              unsigned short* __restrict__ kb,
              unsigned short* __restrict__ vbT,
              int M, int N, int K)
{
    __shared__ __attribute__((aligned(16))) unsigned short U[17408]; // 34.8 KB
    unsigned short* Al0 = U;             // 128*32
    unsigned short* Bl0 = U + 4096;
    unsigned short* Al1 = U + 8192;
    unsigned short* Bl1 = U + 12288;

    const int tid  = threadIdx.x;
    const int wave = tid >> 6;
    const int lane = tid & 63;
    const int m0 = blockIdx.y * 128;
    const int n0 = blockIdx.x * 128;

    const int wm = (wave >> 1) * 64;
    const int wn = (wave & 1) * 64;
    const int quad = lane >> 4;
    const int l16  = lane & 15;

    const int srow = lane >> 2;          // 0..15
    const int scol = (lane & 3) * 8;     // 0,8,16,24

    f32x4 acc[4][4] = {};

    for (int k0 = 0; k0 < K; k0 += 64) {
        __syncthreads();
#pragma unroll
        for (int l = 0; l < 2; ++l) {
            const int r = l * 64 + wave * 16 + srow;
            const unsigned short* gA = A + (size_t)(m0 + r) * K + k0 + scol;
            const unsigned short* gB = B + (size_t)(n0 + r) * K + k0 + scol;
            __builtin_amdgcn_global_load_lds((gptr_t)gA,        (lptr_t)&Al0[r * 32 + scol], 16, 0, 0);
            __builtin_amdgcn_global_load_lds((gptr_t)gB,        (lptr_t)&Bl0[r * 32 + scol], 16, 0, 0);
            __builtin_amdgcn_global_load_lds((gptr_t)(gA + 32), (lptr_t)&Al1[r * 32 + scol], 16, 0, 0);
            __builtin_amdgcn_global_load_lds((gptr_t)(gB + 32), (lptr_t)&Bl1[r * 32 + scol], 16, 0, 0);
        }
        __syncthreads();

#pragma unroll
        for (int kh = 0; kh < 2; ++kh) {
            const unsigned short* Ap = kh ? Al1 : Al0;
            const unsigned short* Bp = kh ? Bl1 : Bl0;
            bf16x8 af[4], bf[4];
#pragma unroll
            for (int i = 0; i < 4; ++i)
                af[i] = *(const bf16x8*)&Ap[(wm + i * 16 + l16) * 32 + quad * 8];
#pragma unroll
            for (int j = 0; j < 4; ++j)
                bf[j] = *(const bf16x8*)&Bp[(wn + j * 16 + l16) * 32 + quad * 8];
#pragma unroll
            for (int i = 0; i < 4; ++i)
#pragma unroll
                for (int j = 0; j < 4; ++j)
                    acc[i][j] = __builtin_amdgcn_mfma_f32_16x16x32_bf16(af[i], bf[j], acc[i][j], 0, 0, 0);
        }
    }

    __syncthreads();   // all waves done reading staging before Tw overwrites

    // ---- epilogue ----
    const int which = (n0 >> 10);   // 0=q 1=k 2=v, uniform per block
    unsigned short* Tw = U + wave * 4352;   // 64*68 per wave

    if (which != 2) {
        float invf[2];
#pragma unroll
        for (int jp = 0; jp < 2; ++jp)
            invf[jp] = exp2f(-(float)(jp * 16 + l16) * 0.41524101186092f);
#pragma unroll
        for (int i = 0; i < 4; ++i) {
            const int tb = (m0 + wm + i * 16 + quad * 4) & 2047;
#pragma unroll
            for (int jp = 0; jp < 2; ++jp)
#pragma unroll
                for (int r = 0; r < 4; ++r) {
                    float s, c;
                    __sincosf((float)(tb + r) * invf[jp], &s, &c);
                    float x1 = acc[i][jp][r], x2 = acc[i][jp + 2][r];
                    acc[i][jp][r]     = x1 * c - x2 * s;
                    acc[i][jp + 2][r] = x2 * c + x1 * s;
                }
        }
#pragma unroll
        for (int i = 0; i < 4; ++i)
#pragma unroll
            for (int j = 0; j < 4; ++j)
#pragma unroll
                for (int r = 0; r < 4; ++r)
                    Tw[(i * 16 + quad * 4 + r) * 68 + j * 16 + l16] = f2bf(acc[i][j][r]);
    } else {
#pragma unroll
        for (int i = 0; i < 4; ++i)
#pragma unroll
            for (int j = 0; j < 4; ++j) {
                ushort4 pv;
                pv.x = f2bf(acc[i][j][0]); pv.y = f2bf(acc[i][j][1]);
                pv.z = f2bf(acc[i][j][2]); pv.w = f2bf(acc[i][j][3]);
                *(ushort4*)&Tw[(j * 16 + l16) * 68 + i * 16 + quad * 4] = pv;
            }
    }

    {
        const int h   = ((n0 + wn) >> 6) & 15;
        const int nb  = (m0 + wm) >> 11;
        const int tw0 = (m0 + wm) & 2047;
        const int lr8 = lane >> 3;          // 0..7
        const int lc8 = (lane & 7) * 8;     // element offset in row
        if (which != 2) {
            unsigned short* dst = (which == 0 ? qb : kb);
            unsigned short* gb = dst + (((size_t)nb * 16 + h) * SEQ + tw0) * 64;
#pragma unroll
            for (int c = 0; c < 8; ++c) {
                const int row = c * 8 + lr8;
                ushort4 lo = *(const ushort4*)&Tw[row * 68 + lc8];
                ushort4 hi = *(const ushort4*)&Tw[row * 68 + lc8 + 4];
                ushort8_t v8 = {lo.x, lo.y, lo.z, lo.w, hi.x, hi.y, hi.z, hi.w};
                *(ushort8_t*)&gb[row * 64 + lc8] = v8;
            }
        } else {
            unsigned short* gb = vbT + ((size_t)nb * 16 + h) * 64 * SEQ + tw0;
#pragma unroll
            for (int c = 0; c < 8; ++c) {
                const int drow = c * 8 + lr8;
                ushort4 lo = *(const ushort4*)&Tw[drow * 68 + lc8];
                ushort4 hi = *(const ushort4*)&Tw[drow * 68 + lc8 + 4];
                ushort8_t v8 = {lo.x, lo.y, lo.z, lo.w, hi.x, hi.y, hi.z, hi.w};
                *(ushort8_t*)&gb[(size_t)drow * SEQ + lc8] = v8;
            }
        }
    }
}

// ---------------------------------------------------------------------------
// Out-projection GEMM (NT), fp32 out + bias. BM=64, BK=64 two panels.
// ---------------------------------------------------------------------------
__global__ __launch_bounds__(256, 4)
void gemm_out(const unsigned short* __restrict__ A,
              const unsigned short* __restrict__ B,
              const float* __restrict__ bias, float* __restrict__ C,
              int M, int N, int K)
{
    __shared__ __attribute__((aligned(16))) unsigned short Al0[64 * 32];
    __shared__ __attribute__((aligned(16))) unsigned short Al1[64 * 32];
    __shared__ __attribute__((aligned(16))) unsigned short Bl0[128 * 32];
    __shared__ __attribute__((aligned(16))) unsigned short Bl1[128 * 32];

    const int tid  = threadIdx.x;
    const int wave = tid >> 6;
    const int lane = tid & 63;
    const int m0 = blockIdx.y * 64;
    const int n0 = blockIdx.x * 128;

    const int wm = (wave >> 1) * 32;
    const int wn = (wave & 1) * 64;
    const int quad = lane >> 4;
    const int l16  = lane & 15;

    const int srow = lane >> 2;
    const int scol = (lane & 3) * 8;

    f32x4 acc[2][4] = {};

    for (int k0 = 0; k0 < K; k0 += 64) {
        __syncthreads();
        {
            const int r = wave * 16 + srow;        // 0..63
            const unsigned short* gA = A + (size_t)(m0 + r) * K + k0 + scol;
            __builtin_amdgcn_global_load_lds((gptr_t)gA,        (lptr_t)&Al0[r * 32 + scol], 16, 0, 0);
            __builtin_amdgcn_global_load_lds((gptr_t)(gA + 32), (lptr_t)&Al1[r * 32 + scol], 16, 0, 0);
#pragma unroll
            for (int l = 0; l < 2; ++l) {
                const int rb = l * 64 + wave * 16 + srow;
                const unsigned short* gB = B + (size_t)(n0 + rb) * K + k0 + scol;
                __builtin_amdgcn_global_load_lds((gptr_t)gB,        (lptr_t)&Bl0[rb * 32 + scol], 16, 0, 0);
                __builtin_amdgcn_global_load_lds((gptr_t)(gB + 32), (lptr_t)&Bl1[rb * 32 + scol], 16, 0, 0);
            }
        }
        __syncthreads();

#pragma unroll
        for (int kh = 0; kh < 2; ++kh) {
            const unsigned short* Ap = kh ? Al1 : Al0;
            const unsigned short* Bp = kh ? Bl1 : Bl0;
            bf16x8 af[2], bf[4];
#pragma unroll
            for (int i = 0; i < 2; ++i)
                af[i] = *(const bf16x8*)&Ap[(wm + i * 16 + l16) * 32 + quad * 8];
#pragma unroll
            for (int j = 0; j < 4; ++j)
                bf[j] = *(const bf16x8*)&Bp[(wn + j * 16 + l16) * 32 + quad * 8];
#pragma unroll
            for (int i = 0; i < 2; ++i)
#pragma unroll
                for (int j = 0; j < 4; ++j)
                    acc[i][j] = __builtin_amdgcn_mfma_f32_16x16x32_bf16(af[i], bf[j], acc[i][j], 0, 0, 0);
        }
    }

#pragma unroll
    for (int i = 0; i < 2; ++i) {
        const int row_base = m0 + wm + i * 16 + quad * 4;
#pragma unroll
        for (int j = 0; j < 4; ++j) {
            const int col = n0 + wn + j * 16 + l16;
            const float bv = bias[col];
#pragma unroll
            for (int r = 0; r < 4; ++r)
                C[(size_t)(row_base + r) * N + col] = acc[i][j][r] + bv;
        }
    }
}

// ---------------------------------------------------------------------------
// Banded MFMA flash attention — single-sweep, block-staged V, XCD-swizzled.
// R11 post-mortem: FETCH 43.6 MB at 1.09 TB/s = band re-reads (each key in
// ~5 adjacent t-blocks' bands) missing the per-XCD L2 because consecutive
// t-blocks dispatch round-robin across XCDs. Swizzle: 1D grid, presumed
// XCD = blockIdx.x & 7; h = xcd + 8*(g&1) pins all 32 t-blocks of each
// (h,n) stream to ONE XCD -> band overlap served from its 4 MB L2
// (~160 KB sliding window per stream). Pure scheduling change.
// ---------------------------------------------------------------------------
__global__ __launch_bounds__(256, 3)
void attn_mfma(const unsigned short* __restrict__ qb,
               const unsigned short* __restrict__ kb,
               const unsigned short* __restrict__ vbT,
               unsigned short* __restrict__ attnb)
{
    __shared__ __attribute__((aligned(16))) unsigned short Vl[64 * 328]; // [d][trel]
    __shared__ __attribute__((aligned(16))) unsigned short Pl[4][16 * 40];

    const int tid  = threadIdx.x;
    const int w    = tid >> 6;
    const int lane = tid & 63;
    const int quad = lane >> 4;
    const int l16  = lane & 15;

    // XCD-aware decode: xcd = d&7 stays fixed for a whole (h,n) t-sweep
    const int dblk = blockIdx.x;            // 0..1023
    const int xcd  = dblk & 7;
    const int g    = dblk >> 3;             // 0..127
    const int h    = xcd + 8 * (g & 1);
    const int nB   = (g >> 1) & 1;
    const int t0   = (g >> 2) * 64;         // 0..1984
    const int nh   = nB * 16 + h;

    const int klo_b = max(0, t0 - WIN_L) & ~31;     // block stage origin

    // ---- stage V band: 64 rows x 328 cols (41 segs of 8), coalesced ----
    {
        const unsigned short* vbase = vbT + (size_t)nh * 64 * SEQ;
        for (int s = tid; s < 64 * 41; s += 256) {
            const int row = s / 41;
            const int seg = s - row * 41;
            const int tsrc = min(klo_b + seg * 8, SEQ - 8);   // finite clamp
            ushort8_t v = *(const ushort8_t*)(vbase + (size_t)row * SEQ + tsrc);
            *(ushort8_t*)&Vl[row * 328 + seg * 8] = v;
        }
    }
    __syncthreads();

    const int tw  = t0 + w * 16;
    const int klo = max(0, tw - WIN_L) & ~31;
    const int khi = min(SEQ, tw + 16 + WIN_R);          // exclusive
    const int nchunk = (khi - klo + 31) >> 5;           // <= 9

    const unsigned short* qrow = qb + ((size_t)nh * SEQ + tw + l16) * 64;
    bf16x8 aq0 = *(const bf16x8*)(qrow + quad * 8);
    bf16x8 aq1 = *(const bf16x8*)(qrow + 32 + quad * 8);

    const unsigned short* kbase = kb + (size_t)nh * SEQ * 64;
    unsigned short* Pw = &Pl[w][0];

    const int trow = tw + quad * 4;

    f32x4 oacc[4] = {};
    float sm[4] = {0.f, 0.f, 0.f, 0.f};

    for (int kc = 0; kc < nchunk; ++kc) {
        const int s0 = klo + kc * 32;
        // ---- QK, interleaved keys: keyA = s0+2*l16, keyB = keyA+1 ----
        const int keyA = s0 + 2 * l16;
        const int keyB = keyA + 1;
        const unsigned short* kpA = kbase + (size_t)min(keyA, SEQ - 1) * 64;
        const unsigned short* kpB = kbase + (size_t)min(keyB, SEQ - 1) * 64;
        bf16x8 bkA0 = *(const bf16x8*)(kpA + quad * 8);
        bf16x8 bkA1 = *(const bf16x8*)(kpA + 32 + quad * 8);
        bf16x8 bkB0 = *(const bf16x8*)(kpB + quad * 8);
        bf16x8 bkB1 = *(const bf16x8*)(kpB + 32 + quad * 8);
        f32x4 sa = {0.f, 0.f, 0.f, 0.f};
        f32x4 sb = {0.f, 0.f, 0.f, 0.f};
        sa = __builtin_amdgcn_mfma_f32_16x16x32_bf16(aq0, bkA0, sa, 0, 0, 0);
        sa = __builtin_amdgcn_mfma_f32_16x16x32_bf16(aq1, bkA1, sa, 0, 0, 0);
        sb = __builtin_amdgcn_mfma_f32_16x16x32_bf16(aq0, bkB0, sb, 0, 0, 0);
        sb = __builtin_amdgcn_mfma_f32_16x16x32_bf16(aq1, bkB1, sb, 0, 0, 0);

        // ---- mask + exp + row-sum + packed P write (bf16x2 per r) ----
#pragma unroll
        for (int r = 0; r < 4; ++r) {
            const int t = trow + r;
            const bool vA = (keyA < khi) && (keyA >= t - WIN_L) && (keyA <= t + WIN_R);
            const bool vB = (keyB < khi) && (keyB >= t - WIN_L) && (keyB <= t + WIN_R);
            float p0 = vA ? __expf(sa[r] * 0.125f) : 0.f;
            float p1 = vB ? __expf(sb[r] * 0.125f) : 0.f;
            sm[r] += p0 + p1;
            unsigned pk = (unsigned)f2bf(p0) | ((unsigned)f2bf(p1) << 16);
            *(unsigned*)&Pw[(quad * 4 + r) * 40 + 2 * l16] = pk;
        }

        // ---- PV: A = P[q][key] frag, B = V from block LDS ----
        bf16x8 pf = *(const bf16x8*)&Pw[l16 * 40 + quad * 8];
        const int rel = s0 - klo_b + quad * 8;
#pragma unroll
        for (int j = 0; j < 4; ++j) {
            bf16x8 vf = *(const bf16x8*)&Vl[(j * 16 + l16) * 328 + rel];
            oacc[j] = __builtin_amdgcn_mfma_f32_16x16x32_bf16(pf, vf, oacc[j], 0, 0, 0);
        }
    }

    // ---- normalize: reduce sm over the 16 lanes sharing each row group ----
#pragma unroll
    for (int r = 0; r < 4; ++r) {
#pragma unroll
        for (int o = 8; o >= 1; o >>= 1) sm[r] += __shfl_xor(sm[r], o, 64);
        sm[r] = 1.0f / sm[r];
    }

    // ---- store: O row = quad*4+r, col = j*16+l16 ----
#pragma unroll
    for (int j = 0; j < 4; ++j)
#pragma unroll
        for (int r = 0; r < 4; ++r) {
            const int t = trow + r;
            attnb[((size_t)(nB * SEQ + t)) * D_MODEL + h * 64 + j * 16 + l16] =
                f2bf(oacc[j][r] * sm[r]);
        }
}

// ---------------------------------------------------------------------------
extern "C" void kernel_launch(void* const* d_in, const int* in_sizes, int n_in,
                              void* d_out, int out_size, void* d_ws, size_t ws_size,
                              hipStream_t stream)
{
    (void)in_sizes; (void)n_in; (void)out_size; (void)ws_size;
    const float* x     = (const float*)d_in[0];
    const float* w_qkv = (const float*)d_in[1];
    const float* w_out = (const float*)d_in[2];
    const float* b_out = (const float*)d_in[3];
    float* out = (float*)d_out;

    const int M = BATCH * SEQ;                 // 4096

    // ws layout (ushorts), 41.9 MB total:
    //   qb | kb | vbT | wob | xb | wqb   (attnb reuses xb after QKV GEMM)
    unsigned short* qb  = (unsigned short*)d_ws;
    unsigned short* kb  = qb  + (size_t)4194304;
    unsigned short* vbT = kb  + (size_t)4194304;
    unsigned short* wob = vbT + (size_t)4194304;
    unsigned short* xb  = wob + (size_t)1048576;
    unsigned short* wqb = xb  + (size_t)4194304;
    unsigned short* attnb = xb;

    dim3 blk(256);

    // 0) fp32 -> bf16 conversions (single launch)
    cvt_all<<<dim3((NX_ELEM + NW_ELEM + NO_ELEM) / 4 / 256), blk, 0, stream>>>(
        x, w_qkv, w_out, xb, wqb, wob);

    // 1) fused QKV projection + RoPE -> qb,kb [n,h,t,64], vbT [n,h,64,t] (bf16)
    gemm_qkv<<<dim3(3 * D_MODEL / 128, M / 128), blk, 0, stream>>>(
        xb, wqb, qb, kb, vbT, M, 3 * D_MODEL, D_MODEL);

    // 2) banded MFMA attention (XCD-swizzled 1D grid) -> attnb
    attn_mfma<<<dim3(1024), blk, 0, stream>>>(qb, kb, vbT, attnb);

    // 3) out = attn @ w_out^T + b_out   (BM=64: grid 8 x 64 = 512 blocks)
    gemm_out<<<dim3(D_MODEL / 128, M / 64), blk, 0, stream>>>(
        attnb, wob, b_out, out, M, D_MODEL, D_MODEL);
}

// Round 13
// 167.140 us; speedup vs baseline: 1.0053x; 1.0053x over previous
//
#include <hip/hip_runtime.h>
#include <math.h>

#define D_MODEL 1024
#define N_HEADS 16
#define HEAD_DIM 64
#define BATCH 2
#define SEQ 2048
#define WIN_L 127
#define WIN_R 128

typedef float f32x4 __attribute__((ext_vector_type(4)));
typedef __bf16 bf16x8 __attribute__((ext_vector_type(8)));
typedef unsigned short ushort8_t __attribute__((ext_vector_type(8)));

typedef const __attribute__((address_space(1))) void* gptr_t;
typedef __attribute__((address_space(3))) void* lptr_t;

__device__ __forceinline__ unsigned short f2bf(float v) {
    unsigned u = __float_as_uint(v);
    unsigned r = (u + 0x7FFF + ((u >> 16) & 1)) >> 16;   // RNE
    return (unsigned short)r;
}

// ---------------------------------------------------------------------------
// fp32 -> bf16 for all three inputs in one launch.
// ---------------------------------------------------------------------------
#define NX_ELEM (4096 * 1024)
#define NW_ELEM (3072 * 1024)
#define NO_ELEM (1024 * 1024)

__global__ __launch_bounds__(256)
void cvt_all(const float* __restrict__ x, const float* __restrict__ wq,
             const float* __restrict__ wo, unsigned short* __restrict__ xb,
             unsigned short* __restrict__ wqb, unsigned short* __restrict__ wob)
{
    int i = (blockIdx.x * 256 + threadIdx.x) * 4;
    const float* src;
    unsigned short* dst;
    int off;
    if (i < NX_ELEM)                 { src = x;  dst = xb;  off = i; }
    else if (i < NX_ELEM + NW_ELEM)  { src = wq; dst = wqb; off = i - NX_ELEM; }
    else                             { src = wo; dst = wob; off = i - NX_ELEM - NW_ELEM; }
    float4 f = *(const float4*)(src + off);
    ushort4 o;
    o.x = f2bf(f.x); o.y = f2bf(f.y); o.z = f2bf(f.z); o.w = f2bf(f.w);
    *(ushort4*)(dst + off) = o;
}

// ---------------------------------------------------------------------------
// QKV GEMM (NT) with fused RoPE + layout epilogue.  (R9-proven config)
// BK=64 per barrier as two BK=32 panels; (256,3) -> 3 blocks/CU.
// ---------------------------------------------------------------------------
__global__ __launch_bounds__(256, 3)
void gemm_qkv(const unsigned short* __restrict__ A,
              const unsigned short* __restrict__ B,
              unsigned short* __restrict__ qb,
              unsigned short* __restrict__ kb,
              unsigned short* __restrict__ vbT,
              int M, int N, int K)
{
    __shared__ __attribute__((aligned(16))) unsigned short U[17408]; // 34.8 KB
    unsigned short* Al0 = U;             // 128*32
    unsigned short* Bl0 = U + 4096;
    unsigned short* Al1 = U + 8192;
    unsigned short* Bl1 = U + 12288;

    const int tid  = threadIdx.x;
    const int wave = tid >> 6;
    const int lane = tid & 63;
    const int m0 = blockIdx.y * 128;
    const int n0 = blockIdx.x * 128;

    const int wm = (wave >> 1) * 64;
    const int wn = (wave & 1) * 64;
    const int quad = lane >> 4;
    const int l16  = lane & 15;

    const int srow = lane >> 2;          // 0..15
    const int scol = (lane & 3) * 8;     // 0,8,16,24

    f32x4 acc[4][4] = {};

    for (int k0 = 0; k0 < K; k0 += 64) {
        __syncthreads();
#pragma unroll
        for (int l = 0; l < 2; ++l) {
            const int r = l * 64 + wave * 16 + srow;
            const unsigned short* gA = A + (size_t)(m0 + r) * K + k0 + scol;
            const unsigned short* gB = B + (size_t)(n0 + r) * K + k0 + scol;
            __builtin_amdgcn_global_load_lds((gptr_t)gA,        (lptr_t)&Al0[r * 32 + scol], 16, 0, 0);
            __builtin_amdgcn_global_load_lds((gptr_t)gB,        (lptr_t)&Bl0[r * 32 + scol], 16, 0, 0);
            __builtin_amdgcn_global_load_lds((gptr_t)(gA + 32), (lptr_t)&Al1[r * 32 + scol], 16, 0, 0);
            __builtin_amdgcn_global_load_lds((gptr_t)(gB + 32), (lptr_t)&Bl1[r * 32 + scol], 16, 0, 0);
        }
        __syncthreads();

#pragma unroll
        for (int kh = 0; kh < 2; ++kh) {
            const unsigned short* Ap = kh ? Al1 : Al0;
            const unsigned short* Bp = kh ? Bl1 : Bl0;
            bf16x8 af[4], bf[4];
#pragma unroll
            for (int i = 0; i < 4; ++i)
                af[i] = *(const bf16x8*)&Ap[(wm + i * 16 + l16) * 32 + quad * 8];
#pragma unroll
            for (int j = 0; j < 4; ++j)
                bf[j] = *(const bf16x8*)&Bp[(wn + j * 16 + l16) * 32 + quad * 8];
#pragma unroll
            for (int i = 0; i < 4; ++i)
#pragma unroll
                for (int j = 0; j < 4; ++j)
                    acc[i][j] = __builtin_amdgcn_mfma_f32_16x16x32_bf16(af[i], bf[j], acc[i][j], 0, 0, 0);
        }
    }

    __syncthreads();   // all waves done reading staging before Tw overwrites

    // ---- epilogue ----
    const int which = (n0 >> 10);   // 0=q 1=k 2=v, uniform per block
    unsigned short* Tw = U + wave * 4352;   // 64*68 per wave

    if (which != 2) {
        float invf[2];
#pragma unroll
        for (int jp = 0; jp < 2; ++jp)
            invf[jp] = exp2f(-(float)(jp * 16 + l16) * 0.41524101186092f);
#pragma unroll
        for (int i = 0; i < 4; ++i) {
            const int tb = (m0 + wm + i * 16 + quad * 4) & 2047;
#pragma unroll
            for (int jp = 0; jp < 2; ++jp)
#pragma unroll
                for (int r = 0; r < 4; ++r) {
                    float s, c;
                    __sincosf((float)(tb + r) * invf[jp], &s, &c);
                    float x1 = acc[i][jp][r], x2 = acc[i][jp + 2][r];
                    acc[i][jp][r]     = x1 * c - x2 * s;
                    acc[i][jp + 2][r] = x2 * c + x1 * s;
                }
        }
#pragma unroll
        for (int i = 0; i < 4; ++i)
#pragma unroll
            for (int j = 0; j < 4; ++j)
#pragma unroll
                for (int r = 0; r < 4; ++r)
                    Tw[(i * 16 + quad * 4 + r) * 68 + j * 16 + l16] = f2bf(acc[i][j][r]);
    } else {
#pragma unroll
        for (int i = 0; i < 4; ++i)
#pragma unroll
            for (int j = 0; j < 4; ++j) {
                ushort4 pv;
                pv.x = f2bf(acc[i][j][0]); pv.y = f2bf(acc[i][j][1]);
                pv.z = f2bf(acc[i][j][2]); pv.w = f2bf(acc[i][j][3]);
                *(ushort4*)&Tw[(j * 16 + l16) * 68 + i * 16 + quad * 4] = pv;
            }
    }

    {
        const int h   = ((n0 + wn) >> 6) & 15;
        const int nb  = (m0 + wm) >> 11;
        const int tw0 = (m0 + wm) & 2047;
        const int lr8 = lane >> 3;          // 0..7
        const int lc8 = (lane & 7) * 8;     // element offset in row
        if (which != 2) {
            unsigned short* dst = (which == 0 ? qb : kb);
            unsigned short* gb = dst + (((size_t)nb * 16 + h) * SEQ + tw0) * 64;
#pragma unroll
            for (int c = 0; c < 8; ++c) {
                const int row = c * 8 + lr8;
                ushort4 lo = *(const ushort4*)&Tw[row * 68 + lc8];
                ushort4 hi = *(const ushort4*)&Tw[row * 68 + lc8 + 4];
                ushort8_t v8 = {lo.x, lo.y, lo.z, lo.w, hi.x, hi.y, hi.z, hi.w};
                *(ushort8_t*)&gb[row * 64 + lc8] = v8;
            }
        } else {
            unsigned short* gb = vbT + ((size_t)nb * 16 + h) * 64 * SEQ + tw0;
#pragma unroll
            for (int c = 0; c < 8; ++c) {
                const int drow = c * 8 + lr8;
                ushort4 lo = *(const ushort4*)&Tw[drow * 68 + lc8];
                ushort4 hi = *(const ushort4*)&Tw[drow * 68 + lc8 + 4];
                ushort8_t v8 = {lo.x, lo.y, lo.z, lo.w, hi.x, hi.y, hi.z, hi.w};
                *(ushort8_t*)&gb[(size_t)drow * SEQ + lc8] = v8;
            }
        }
    }
}

// ---------------------------------------------------------------------------
// Out-projection GEMM (NT), fp32 out + bias. BM=64, BK=64 two panels.
// ---------------------------------------------------------------------------
__global__ __launch_bounds__(256, 4)
void gemm_out(const unsigned short* __restrict__ A,
              const unsigned short* __restrict__ B,
              const float* __restrict__ bias, float* __restrict__ C,
              int M, int N, int K)
{
    __shared__ __attribute__((aligned(16))) unsigned short Al0[64 * 32];
    __shared__ __attribute__((aligned(16))) unsigned short Al1[64 * 32];
    __shared__ __attribute__((aligned(16))) unsigned short Bl0[128 * 32];
    __shared__ __attribute__((aligned(16))) unsigned short Bl1[128 * 32];

    const int tid  = threadIdx.x;
    const int wave = tid >> 6;
    const int lane = tid & 63;
    const int m0 = blockIdx.y * 64;
    const int n0 = blockIdx.x * 128;

    const int wm = (wave >> 1) * 32;
    const int wn = (wave & 1) * 64;
    const int quad = lane >> 4;
    const int l16  = lane & 15;

    const int srow = lane >> 2;
    const int scol = (lane & 3) * 8;

    f32x4 acc[2][4] = {};

    for (int k0 = 0; k0 < K; k0 += 64) {
        __syncthreads();
        {
            const int r = wave * 16 + srow;        // 0..63
            const unsigned short* gA = A + (size_t)(m0 + r) * K + k0 + scol;
            __builtin_amdgcn_global_load_lds((gptr_t)gA,        (lptr_t)&Al0[r * 32 + scol], 16, 0, 0);
            __builtin_amdgcn_global_load_lds((gptr_t)(gA + 32), (lptr_t)&Al1[r * 32 + scol], 16, 0, 0);
#pragma unroll
            for (int l = 0; l < 2; ++l) {
                const int rb = l * 64 + wave * 16 + srow;
                const unsigned short* gB = B + (size_t)(n0 + rb) * K + k0 + scol;
                __builtin_amdgcn_global_load_lds((gptr_t)gB,        (lptr_t)&Bl0[rb * 32 + scol], 16, 0, 0);
                __builtin_amdgcn_global_load_lds((gptr_t)(gB + 32), (lptr_t)&Bl1[rb * 32 + scol], 16, 0, 0);
            }
        }
        __syncthreads();

#pragma unroll
        for (int kh = 0; kh < 2; ++kh) {
            const unsigned short* Ap = kh ? Al1 : Al0;
            const unsigned short* Bp = kh ? Bl1 : Bl0;
            bf16x8 af[2], bf[4];
#pragma unroll
            for (int i = 0; i < 2; ++i)
                af[i] = *(const bf16x8*)&Ap[(wm + i * 16 + l16) * 32 + quad * 8];
#pragma unroll
            for (int j = 0; j < 4; ++j)
                bf[j] = *(const bf16x8*)&Bp[(wn + j * 16 + l16) * 32 + quad * 8];
#pragma unroll
            for (int i = 0; i < 2; ++i)
#pragma unroll
                for (int j = 0; j < 4; ++j)
                    acc[i][j] = __builtin_amdgcn_mfma_f32_16x16x32_bf16(af[i], bf[j], acc[i][j], 0, 0, 0);
        }
    }

#pragma unroll
    for (int i = 0; i < 2; ++i) {
        const int row_base = m0 + wm + i * 16 + quad * 4;
#pragma unroll
        for (int j = 0; j < 4; ++j) {
            const int col = n0 + wn + j * 16 + l16;
            const float bv = bias[col];
#pragma unroll
            for (int r = 0; r < 4; ++r)
                C[(size_t)(row_base + r) * N + col] = acc[i][j][r] + bv;
        }
    }
}

// ---------------------------------------------------------------------------
// Banded MFMA flash attention — single-sweep, block-staged V, pipelined.
// R12 post-mortem: BW/scatter attacks all ~neutral -> limiter is the serial
// per-chunk chain (QK -> exp -> P LDS write -> P LDS read -> PV) with a
// same-address WAR hazard on the shared P buffer serializing iterations.
// Fixes: (1) double-buffered P (no cross-iter LDS alias -> k+1's QK can
// overlap k's PV); (2) K-frags for chunk k+1 prefetched into registers
// before k's exp/PV (global latency hidden under the tail); (3) exp2f with
// folded constant (compiler can't reassociate __expf(x*0.125) muls).
// LDS 52 KB -> 3 blocks/CU (unchanged).
// ---------------------------------------------------------------------------
__global__ __launch_bounds__(256, 3)
void attn_mfma(const unsigned short* __restrict__ qb,
               const unsigned short* __restrict__ kb,
               const unsigned short* __restrict__ vbT,
               unsigned short* __restrict__ attnb)
{
    __shared__ __attribute__((aligned(16))) unsigned short Vl[64 * 328]; // [d][trel]
    __shared__ __attribute__((aligned(16))) unsigned short Pl[4][2][16 * 40];

    const int tid  = threadIdx.x;
    const int w    = tid >> 6;
    const int lane = tid & 63;
    const int quad = lane >> 4;
    const int l16  = lane & 15;

    const int t0 = blockIdx.x * 64;
    const int h  = blockIdx.y;
    const int nB = blockIdx.z;
    const int nh = nB * 16 + h;

    const int klo_b = max(0, t0 - WIN_L) & ~31;     // block stage origin

    // ---- stage V band: 64 rows x 328 cols (41 segs of 8), coalesced ----
    {
        const unsigned short* vbase = vbT + (size_t)nh * 64 * SEQ;
        for (int s = tid; s < 64 * 41; s += 256) {
            const int row = s / 41;
            const int seg = s - row * 41;
            const int tsrc = min(klo_b + seg * 8, SEQ - 8);   // finite clamp
            ushort8_t v = *(const ushort8_t*)(vbase + (size_t)row * SEQ + tsrc);
            *(ushort8_t*)&Vl[row * 328 + seg * 8] = v;
        }
    }
    __syncthreads();

    const int tw  = t0 + w * 16;
    const int klo = max(0, tw - WIN_L) & ~31;
    const int khi = min(SEQ, tw + 16 + WIN_R);          // exclusive
    const int nchunk = (khi - klo + 31) >> 5;           // <= 9

    const unsigned short* qrow = qb + ((size_t)nh * SEQ + tw + l16) * 64;
    bf16x8 aq0 = *(const bf16x8*)(qrow + quad * 8);
    bf16x8 aq1 = *(const bf16x8*)(qrow + 32 + quad * 8);

    const unsigned short* kbase = kb + (size_t)nh * SEQ * 64;

    const int trow = tw + quad * 4;

    f32x4 oacc[4] = {};
    float sm[4] = {0.f, 0.f, 0.f, 0.f};

    // prologue: K frags for chunk 0
    bf16x8 kA0, kA1, kB0, kB1;
    {
        const int keyA = klo + 2 * l16;
        const unsigned short* kpA = kbase + (size_t)min(keyA, SEQ - 1) * 64;
        const unsigned short* kpB = kbase + (size_t)min(keyA + 1, SEQ - 1) * 64;
        kA0 = *(const bf16x8*)(kpA + quad * 8);
        kA1 = *(const bf16x8*)(kpA + 32 + quad * 8);
        kB0 = *(const bf16x8*)(kpB + quad * 8);
        kB1 = *(const bf16x8*)(kpB + 32 + quad * 8);
    }

    for (int kc = 0; kc < nchunk; ++kc) {
        const int s0 = klo + kc * 32;
        const int keyA = s0 + 2 * l16;
        const int keyB = keyA + 1;

        // ---- prefetch chunk kc+1's K frags (in flight through exp/PV) ----
        bf16x8 nA0 = kA0, nA1 = kA1, nB0 = kB0, nB1 = kB1;
        if (kc + 1 < nchunk) {
            const int kyA = s0 + 32 + 2 * l16;
            const unsigned short* kpA = kbase + (size_t)min(kyA, SEQ - 1) * 64;
            const unsigned short* kpB = kbase + (size_t)min(kyA + 1, SEQ - 1) * 64;
            nA0 = *(const bf16x8*)(kpA + quad * 8);
            nA1 = *(const bf16x8*)(kpA + 32 + quad * 8);
            nB0 = *(const bf16x8*)(kpB + quad * 8);
            nB1 = *(const bf16x8*)(kpB + 32 + quad * 8);
        }

        // ---- QK ----
        f32x4 sa = {0.f, 0.f, 0.f, 0.f};
        f32x4 sb = {0.f, 0.f, 0.f, 0.f};
        sa = __builtin_amdgcn_mfma_f32_16x16x32_bf16(aq0, kA0, sa, 0, 0, 0);
        sa = __builtin_amdgcn_mfma_f32_16x16x32_bf16(aq1, kA1, sa, 0, 0, 0);
        sb = __builtin_amdgcn_mfma_f32_16x16x32_bf16(aq0, kB0, sb, 0, 0, 0);
        sb = __builtin_amdgcn_mfma_f32_16x16x32_bf16(aq1, kB1, sb, 0, 0, 0);

        // ---- mask + exp + row-sum + packed P write (double-buffered) ----
        unsigned short* Pc = &Pl[w][kc & 1][0];
#pragma unroll
        for (int r = 0; r < 4; ++r) {
            const int t = trow + r;
            const bool vA = (keyA < khi) && (keyA >= t - WIN_L) && (keyA <= t + WIN_R);
            const bool vB = (keyB < khi) && (keyB >= t - WIN_L) && (keyB <= t + WIN_R);
            // exp(s/8) = exp2(s * 0.125*log2(e)); folded constant (1 mul)
            float p0 = vA ? exp2f(sa[r] * 0.18033688011f) : 0.f;
            float p1 = vB ? exp2f(sb[r] * 0.18033688011f) : 0.f;
            sm[r] += p0 + p1;
            unsigned pk = (unsigned)f2bf(p0) | ((unsigned)f2bf(p1) << 16);
            *(unsigned*)&Pc[(quad * 4 + r) * 40 + 2 * l16] = pk;
        }

        // ---- PV: A = P frag (same wave), B = V from block LDS ----
        bf16x8 pf = *(const bf16x8*)&Pc[l16 * 40 + quad * 8];
        const int rel = s0 - klo_b + quad * 8;
#pragma unroll
        for (int j = 0; j < 4; ++j) {
            bf16x8 vf = *(const bf16x8*)&Vl[(j * 16 + l16) * 328 + rel];
            oacc[j] = __builtin_amdgcn_mfma_f32_16x16x32_bf16(pf, vf, oacc[j], 0, 0, 0);
        }

        kA0 = nA0; kA1 = nA1; kB0 = nB0; kB1 = nB1;
    }

    // ---- normalize: reduce sm over the 16 lanes sharing each row group ----
#pragma unroll
    for (int r = 0; r < 4; ++r) {
#pragma unroll
        for (int o = 8; o >= 1; o >>= 1) sm[r] += __shfl_xor(sm[r], o, 64);
        sm[r] = 1.0f / sm[r];
    }

    // ---- store: O row = quad*4+r, col = j*16+l16 ----
#pragma unroll
    for (int j = 0; j < 4; ++j)
#pragma unroll
        for (int r = 0; r < 4; ++r) {
            const int t = trow + r;
            attnb[((size_t)(nB * SEQ + t)) * D_MODEL + h * 64 + j * 16 + l16] =
                f2bf(oacc[j][r] * sm[r]);
        }
}

// ---------------------------------------------------------------------------
extern "C" void kernel_launch(void* const* d_in, const int* in_sizes, int n_in,
                              void* d_out, int out_size, void* d_ws, size_t ws_size,
                              hipStream_t stream)
{
    (void)in_sizes; (void)n_in; (void)out_size; (void)ws_size;
    const float* x     = (const float*)d_in[0];
    const float* w_qkv = (const float*)d_in[1];
    const float* w_out = (const float*)d_in[2];
    const float* b_out = (const float*)d_in[3];
    float* out = (float*)d_out;

    const int M = BATCH * SEQ;                 // 4096

    // ws layout (ushorts), 41.9 MB total:
    //   qb | kb | vbT | wob | xb | wqb   (attnb reuses xb after QKV GEMM)
    unsigned short* qb  = (unsigned short*)d_ws;
    unsigned short* kb  = qb  + (size_t)4194304;
    unsigned short* vbT = kb  + (size_t)4194304;
    unsigned short* wob = vbT + (size_t)4194304;
    unsigned short* xb  = wob + (size_t)1048576;
    unsigned short* wqb = xb  + (size_t)4194304;
    unsigned short* attnb = xb;

    dim3 blk(256);

    // 0) fp32 -> bf16 conversions (single launch)
    cvt_all<<<dim3((NX_ELEM + NW_ELEM + NO_ELEM) / 4 / 256), blk, 0, stream>>>(
        x, w_qkv, w_out, xb, wqb, wob);

    // 1) fused QKV projection + RoPE -> qb,kb [n,h,t,64], vbT [n,h,64,t] (bf16)
    gemm_qkv<<<dim3(3 * D_MODEL / 128, M / 128), blk, 0, stream>>>(
        xb, wqb, qb, kb, vbT, M, 3 * D_MODEL, D_MODEL);

    // 2) banded MFMA attention (pipelined single-sweep) -> attnb
    attn_mfma<<<dim3(SEQ / 64, N_HEADS, BATCH), blk, 0, stream>>>(qb, kb, vbT, attnb);

    // 3) out = attn @ w_out^T + b_out   (BM=64: grid 8 x 64 = 512 blocks)
    gemm_out<<<dim3(D_MODEL / 128, M / 64), blk, 0, stream>>>(
        attnb, wob, b_out, out, M, D_MODEL, D_MODEL);
}

// Round 14
// 167.053 us; speedup vs baseline: 1.0058x; 1.0005x over previous
//
#include <hip/hip_runtime.h>
#include <math.h>

#define D_MODEL 1024
#define N_HEADS 16
#define HEAD_DIM 64
#define BATCH 2
#define SEQ 2048
#define WIN_L 127
#define WIN_R 128

typedef float f32x4 __attribute__((ext_vector_type(4)));
typedef __bf16 bf16x8 __attribute__((ext_vector_type(8)));
typedef unsigned short ushort8_t __attribute__((ext_vector_type(8)));

typedef const __attribute__((address_space(1))) void* gptr_t;
typedef __attribute__((address_space(3))) void* lptr_t;

__device__ __forceinline__ unsigned short f2bf(float v) {
    unsigned u = __float_as_uint(v);
    unsigned r = (u + 0x7FFF + ((u >> 16) & 1)) >> 16;   // RNE
    return (unsigned short)r;
}

// ---------------------------------------------------------------------------
// fp32 -> bf16 for all three inputs in one launch.
// ---------------------------------------------------------------------------
#define NX_ELEM (4096 * 1024)
#define NW_ELEM (3072 * 1024)
#define NO_ELEM (1024 * 1024)

__global__ __launch_bounds__(256)
void cvt_all(const float* __restrict__ x, const float* __restrict__ wq,
             const float* __restrict__ wo, unsigned short* __restrict__ xb,
             unsigned short* __restrict__ wqb, unsigned short* __restrict__ wob)
{
    int i = (blockIdx.x * 256 + threadIdx.x) * 4;
    const float* src;
    unsigned short* dst;
    int off;
    if (i < NX_ELEM)                 { src = x;  dst = xb;  off = i; }
    else if (i < NX_ELEM + NW_ELEM)  { src = wq; dst = wqb; off = i - NX_ELEM; }
    else                             { src = wo; dst = wob; off = i - NX_ELEM - NW_ELEM; }
    float4 f = *(const float4*)(src + off);
    ushort4 o;
    o.x = f2bf(f.x); o.y = f2bf(f.y); o.z = f2bf(f.z); o.w = f2bf(f.w);
    *(ushort4*)(dst + off) = o;
}

// ---------------------------------------------------------------------------
// QKV GEMM (NT) with fused RoPE + layout epilogue.  (R9-proven config)
// BK=64 per barrier as two BK=32 panels; (256,3) -> 3 blocks/CU.
// ---------------------------------------------------------------------------
__global__ __launch_bounds__(256, 3)
void gemm_qkv(const unsigned short* __restrict__ A,
              const unsigned short* __restrict__ B,
              unsigned short* __restrict__ qb,
              unsigned short* __restrict__ kb,
              unsigned short* __restrict__ vbT,
              int M, int N, int K)
{
    __shared__ __attribute__((aligned(16))) unsigned short U[17408]; // 34.8 KB
    unsigned short* Al0 = U;             // 128*32
    unsigned short* Bl0 = U + 4096;
    unsigned short* Al1 = U + 8192;
    unsigned short* Bl1 = U + 12288;

    const int tid  = threadIdx.x;
    const int wave = tid >> 6;
    const int lane = tid & 63;
    const int m0 = blockIdx.y * 128;
    const int n0 = blockIdx.x * 128;

    const int wm = (wave >> 1) * 64;
    const int wn = (wave & 1) * 64;
    const int quad = lane >> 4;
    const int l16  = lane & 15;

    const int srow = lane >> 2;          // 0..15
    const int scol = (lane & 3) * 8;     // 0,8,16,24

    f32x4 acc[4][4] = {};

    for (int k0 = 0; k0 < K; k0 += 64) {
        __syncthreads();
#pragma unroll
        for (int l = 0; l < 2; ++l) {
            const int r = l * 64 + wave * 16 + srow;
            const unsigned short* gA = A + (size_t)(m0 + r) * K + k0 + scol;
            const unsigned short* gB = B + (size_t)(n0 + r) * K + k0 + scol;
            __builtin_amdgcn_global_load_lds((gptr_t)gA,        (lptr_t)&Al0[r * 32 + scol], 16, 0, 0);
            __builtin_amdgcn_global_load_lds((gptr_t)gB,        (lptr_t)&Bl0[r * 32 + scol], 16, 0, 0);
            __builtin_amdgcn_global_load_lds((gptr_t)(gA + 32), (lptr_t)&Al1[r * 32 + scol], 16, 0, 0);
            __builtin_amdgcn_global_load_lds((gptr_t)(gB + 32), (lptr_t)&Bl1[r * 32 + scol], 16, 0, 0);
        }
        __syncthreads();

#pragma unroll
        for (int kh = 0; kh < 2; ++kh) {
            const unsigned short* Ap = kh ? Al1 : Al0;
            const unsigned short* Bp = kh ? Bl1 : Bl0;
            bf16x8 af[4], bf[4];
#pragma unroll
            for (int i = 0; i < 4; ++i)
                af[i] = *(const bf16x8*)&Ap[(wm + i * 16 + l16) * 32 + quad * 8];
#pragma unroll
            for (int j = 0; j < 4; ++j)
                bf[j] = *(const bf16x8*)&Bp[(wn + j * 16 + l16) * 32 + quad * 8];
#pragma unroll
            for (int i = 0; i < 4; ++i)
#pragma unroll
                for (int j = 0; j < 4; ++j)
                    acc[i][j] = __builtin_amdgcn_mfma_f32_16x16x32_bf16(af[i], bf[j], acc[i][j], 0, 0, 0);
        }
    }

    __syncthreads();   // all waves done reading staging before Tw overwrites

    // ---- epilogue ----
    const int which = (n0 >> 10);   // 0=q 1=k 2=v, uniform per block
    unsigned short* Tw = U + wave * 4352;   // 64*68 per wave

    if (which != 2) {
        float invf[2];
#pragma unroll
        for (int jp = 0; jp < 2; ++jp)
            invf[jp] = exp2f(-(float)(jp * 16 + l16) * 0.41524101186092f);
#pragma unroll
        for (int i = 0; i < 4; ++i) {
            const int tb = (m0 + wm + i * 16 + quad * 4) & 2047;
#pragma unroll
            for (int jp = 0; jp < 2; ++jp)
#pragma unroll
                for (int r = 0; r < 4; ++r) {
                    float s, c;
                    __sincosf((float)(tb + r) * invf[jp], &s, &c);
                    float x1 = acc[i][jp][r], x2 = acc[i][jp + 2][r];
                    acc[i][jp][r]     = x1 * c - x2 * s;
                    acc[i][jp + 2][r] = x2 * c + x1 * s;
                }
        }
#pragma unroll
        for (int i = 0; i < 4; ++i)
#pragma unroll
            for (int j = 0; j < 4; ++j)
#pragma unroll
                for (int r = 0; r < 4; ++r)
                    Tw[(i * 16 + quad * 4 + r) * 68 + j * 16 + l16] = f2bf(acc[i][j][r]);
    } else {
#pragma unroll
        for (int i = 0; i < 4; ++i)
#pragma unroll
            for (int j = 0; j < 4; ++j) {
                ushort4 pv;
                pv.x = f2bf(acc[i][j][0]); pv.y = f2bf(acc[i][j][1]);
                pv.z = f2bf(acc[i][j][2]); pv.w = f2bf(acc[i][j][3]);
                *(ushort4*)&Tw[(j * 16 + l16) * 68 + i * 16 + quad * 4] = pv;
            }
    }

    {
        const int h   = ((n0 + wn) >> 6) & 15;
        const int nb  = (m0 + wm) >> 11;
        const int tw0 = (m0 + wm) & 2047;
        const int lr8 = lane >> 3;          // 0..7
        const int lc8 = (lane & 7) * 8;     // element offset in row
        if (which != 2) {
            unsigned short* dst = (which == 0 ? qb : kb);
            unsigned short* gb = dst + (((size_t)nb * 16 + h) * SEQ + tw0) * 64;
#pragma unroll
            for (int c = 0; c < 8; ++c) {
                const int row = c * 8 + lr8;
                ushort4 lo = *(const ushort4*)&Tw[row * 68 + lc8];
                ushort4 hi = *(const ushort4*)&Tw[row * 68 + lc8 + 4];
                ushort8_t v8 = {lo.x, lo.y, lo.z, lo.w, hi.x, hi.y, hi.z, hi.w};
                *(ushort8_t*)&gb[row * 64 + lc8] = v8;
            }
        } else {
            unsigned short* gb = vbT + ((size_t)nb * 16 + h) * 64 * SEQ + tw0;
#pragma unroll
            for (int c = 0; c < 8; ++c) {
                const int drow = c * 8 + lr8;
                ushort4 lo = *(const ushort4*)&Tw[drow * 68 + lc8];
                ushort4 hi = *(const ushort4*)&Tw[drow * 68 + lc8 + 4];
                ushort8_t v8 = {lo.x, lo.y, lo.z, lo.w, hi.x, hi.y, hi.z, hi.w};
                *(ushort8_t*)&gb[(size_t)drow * SEQ + lc8] = v8;
            }
        }
    }
}

// ---------------------------------------------------------------------------
// Out-projection GEMM (NT), fp32 out + bias. BM=64, BK=64 two panels.
// ---------------------------------------------------------------------------
__global__ __launch_bounds__(256, 4)
void gemm_out(const unsigned short* __restrict__ A,
              const unsigned short* __restrict__ B,
              const float* __restrict__ bias, float* __restrict__ C,
              int M, int N, int K)
{
    __shared__ __attribute__((aligned(16))) unsigned short Al0[64 * 32];
    __shared__ __attribute__((aligned(16))) unsigned short Al1[64 * 32];
    __shared__ __attribute__((aligned(16))) unsigned short Bl0[128 * 32];
    __shared__ __attribute__((aligned(16))) unsigned short Bl1[128 * 32];

    const int tid  = threadIdx.x;
    const int wave = tid >> 6;
    const int lane = tid & 63;
    const int m0 = blockIdx.y * 64;
    const int n0 = blockIdx.x * 128;

    const int wm = (wave >> 1) * 32;
    const int wn = (wave & 1) * 64;
    const int quad = lane >> 4;
    const int l16  = lane & 15;

    const int srow = lane >> 2;
    const int scol = (lane & 3) * 8;

    f32x4 acc[2][4] = {};

    for (int k0 = 0; k0 < K; k0 += 64) {
        __syncthreads();
        {
            const int r = wave * 16 + srow;        // 0..63
            const unsigned short* gA = A + (size_t)(m0 + r) * K + k0 + scol;
            __builtin_amdgcn_global_load_lds((gptr_t)gA,        (lptr_t)&Al0[r * 32 + scol], 16, 0, 0);
            __builtin_amdgcn_global_load_lds((gptr_t)(gA + 32), (lptr_t)&Al1[r * 32 + scol], 16, 0, 0);
#pragma unroll
            for (int l = 0; l < 2; ++l) {
                const int rb = l * 64 + wave * 16 + srow;
                const unsigned short* gB = B + (size_t)(n0 + rb) * K + k0 + scol;
                __builtin_amdgcn_global_load_lds((gptr_t)gB,        (lptr_t)&Bl0[rb * 32 + scol], 16, 0, 0);
                __builtin_amdgcn_global_load_lds((gptr_t)(gB + 32), (lptr_t)&Bl1[rb * 32 + scol], 16, 0, 0);
            }
        }
        __syncthreads();

#pragma unroll
        for (int kh = 0; kh < 2; ++kh) {
            const unsigned short* Ap = kh ? Al1 : Al0;
            const unsigned short* Bp = kh ? Bl1 : Bl0;
            bf16x8 af[2], bf[4];
#pragma unroll
            for (int i = 0; i < 2; ++i)
                af[i] = *(const bf16x8*)&Ap[(wm + i * 16 + l16) * 32 + quad * 8];
#pragma unroll
            for (int j = 0; j < 4; ++j)
                bf[j] = *(const bf16x8*)&Bp[(wn + j * 16 + l16) * 32 + quad * 8];
#pragma unroll
            for (int i = 0; i < 2; ++i)
#pragma unroll
                for (int j = 0; j < 4; ++j)
                    acc[i][j] = __builtin_amdgcn_mfma_f32_16x16x32_bf16(af[i], bf[j], acc[i][j], 0, 0, 0);
        }
    }

#pragma unroll
    for (int i = 0; i < 2; ++i) {
        const int row_base = m0 + wm + i * 16 + quad * 4;
#pragma unroll
        for (int j = 0; j < 4; ++j) {
            const int col = n0 + wn + j * 16 + l16;
            const float bv = bias[col];
#pragma unroll
            for (int r = 0; r < 4; ++r)
                C[(size_t)(row_base + r) * N + col] = acc[i][j][r] + bv;
        }
    }
}

// ---------------------------------------------------------------------------
// Banded MFMA flash attention — single-sweep, async block-staged V, pipelined.
// R13 post-mortem: the V staging loop (load 16B -> ds_write, x10/lane) was a
// latency serialization — every ds_write forced a vmcnt wait, so the ~10
// loads never overlapped (~9k stall cycles/wave behind the barrier). Fix:
// stage V via global_load_lds (direct-to-LDS, fire-and-forget; drained once
// by the barrier). The flat dest s*16B with s = k*256 + wave*64 + lane is
// wave-uniform-base + lane*16 as required; 328 = 41*8 so each 8-ushort seg
// stays in one V row; clamp tail only feeds masked keys (P=0).
// ---------------------------------------------------------------------------
__global__ __launch_bounds__(256, 3)
void attn_mfma(const unsigned short* __restrict__ qb,
               const unsigned short* __restrict__ kb,
               const unsigned short* __restrict__ vbT,
               unsigned short* __restrict__ attnb)
{
    __shared__ __attribute__((aligned(16))) unsigned short Vl[64 * 328]; // [d][trel]
    __shared__ __attribute__((aligned(16))) unsigned short Pl[4][2][16 * 40];

    const int tid  = threadIdx.x;
    const int w    = tid >> 6;
    const int lane = tid & 63;
    const int quad = lane >> 4;
    const int l16  = lane & 15;

    const int t0 = blockIdx.x * 64;
    const int h  = blockIdx.y;
    const int nB = blockIdx.z;
    const int nh = nB * 16 + h;

    const int klo_b = max(0, t0 - WIN_L) & ~31;     // block stage origin

    // ---- stage V band via async global->LDS (41 KB, ~10 loads/lane) ----
    {
        const unsigned short* vbase = vbT + (size_t)nh * 64 * SEQ;
#pragma unroll
        for (int k = 0; k < 11; ++k) {
            const int s = k * 256 + tid;            // seg index, 16 B each
            if (s < 64 * 41) {
                const int row = s / 41;
                const int seg = s - row * 41;
                const int tsrc = min(klo_b + seg * 8, SEQ - 8);   // finite clamp
                __builtin_amdgcn_global_load_lds(
                    (gptr_t)(vbase + (size_t)row * SEQ + tsrc),
                    (lptr_t)&Vl[s * 8], 16, 0, 0);
            }
        }
    }
    __syncthreads();   // drains all staging loads

    const int tw  = t0 + w * 16;
    const int klo = max(0, tw - WIN_L) & ~31;
    const int khi = min(SEQ, tw + 16 + WIN_R);          // exclusive
    const int nchunk = (khi - klo + 31) >> 5;           // <= 9

    const unsigned short* qrow = qb + ((size_t)nh * SEQ + tw + l16) * 64;
    bf16x8 aq0 = *(const bf16x8*)(qrow + quad * 8);
    bf16x8 aq1 = *(const bf16x8*)(qrow + 32 + quad * 8);

    const unsigned short* kbase = kb + (size_t)nh * SEQ * 64;

    const int trow = tw + quad * 4;

    f32x4 oacc[4] = {};
    float sm[4] = {0.f, 0.f, 0.f, 0.f};

    // prologue: K frags for chunk 0
    bf16x8 kA0, kA1, kB0, kB1;
    {
        const int keyA = klo + 2 * l16;
        const unsigned short* kpA = kbase + (size_t)min(keyA, SEQ - 1) * 64;
        const unsigned short* kpB = kbase + (size_t)min(keyA + 1, SEQ - 1) * 64;
        kA0 = *(const bf16x8*)(kpA + quad * 8);
        kA1 = *(const bf16x8*)(kpA + 32 + quad * 8);
        kB0 = *(const bf16x8*)(kpB + quad * 8);
        kB1 = *(const bf16x8*)(kpB + 32 + quad * 8);
    }

    for (int kc = 0; kc < nchunk; ++kc) {
        const int s0 = klo + kc * 32;
        const int keyA = s0 + 2 * l16;
        const int keyB = keyA + 1;

        // ---- prefetch chunk kc+1's K frags (in flight through exp/PV) ----
        bf16x8 nA0 = kA0, nA1 = kA1, nB0 = kB0, nB1 = kB1;
        if (kc + 1 < nchunk) {
            const int kyA = s0 + 32 + 2 * l16;
            const unsigned short* kpA = kbase + (size_t)min(kyA, SEQ - 1) * 64;
            const unsigned short* kpB = kbase + (size_t)min(kyA + 1, SEQ - 1) * 64;
            nA0 = *(const bf16x8*)(kpA + quad * 8);
            nA1 = *(const bf16x8*)(kpA + 32 + quad * 8);
            nB0 = *(const bf16x8*)(kpB + quad * 8);
            nB1 = *(const bf16x8*)(kpB + 32 + quad * 8);
        }

        // ---- QK ----
        f32x4 sa = {0.f, 0.f, 0.f, 0.f};
        f32x4 sb = {0.f, 0.f, 0.f, 0.f};
        sa = __builtin_amdgcn_mfma_f32_16x16x32_bf16(aq0, kA0, sa, 0, 0, 0);
        sa = __builtin_amdgcn_mfma_f32_16x16x32_bf16(aq1, kA1, sa, 0, 0, 0);
        sb = __builtin_amdgcn_mfma_f32_16x16x32_bf16(aq0, kB0, sb, 0, 0, 0);
        sb = __builtin_amdgcn_mfma_f32_16x16x32_bf16(aq1, kB1, sb, 0, 0, 0);

        // ---- mask + exp + row-sum + packed P write (double-buffered) ----
        unsigned short* Pc = &Pl[w][kc & 1][0];
#pragma unroll
        for (int r = 0; r < 4; ++r) {
            const int t = trow + r;
            const bool vA = (keyA < khi) && (keyA >= t - WIN_L) && (keyA <= t + WIN_R);
            const bool vB = (keyB < khi) && (keyB >= t - WIN_L) && (keyB <= t + WIN_R);
            // exp(s/8) = exp2(s * 0.125*log2(e)); folded constant (1 mul)
            float p0 = vA ? exp2f(sa[r] * 0.18033688011f) : 0.f;
            float p1 = vB ? exp2f(sb[r] * 0.18033688011f) : 0.f;
            sm[r] += p0 + p1;
            unsigned pk = (unsigned)f2bf(p0) | ((unsigned)f2bf(p1) << 16);
            *(unsigned*)&Pc[(quad * 4 + r) * 40 + 2 * l16] = pk;
        }

        // ---- PV: A = P frag (same wave), B = V from block LDS ----
        bf16x8 pf = *(const bf16x8*)&Pc[l16 * 40 + quad * 8];
        const int rel = s0 - klo_b + quad * 8;
#pragma unroll
        for (int j = 0; j < 4; ++j) {
            bf16x8 vf = *(const bf16x8*)&Vl[(j * 16 + l16) * 328 + rel];
            oacc[j] = __builtin_amdgcn_mfma_f32_16x16x32_bf16(pf, vf, oacc[j], 0, 0, 0);
        }

        kA0 = nA0; kA1 = nA1; kB0 = nB0; kB1 = nB1;
    }

    // ---- normalize: reduce sm over the 16 lanes sharing each row group ----
#pragma unroll
    for (int r = 0; r < 4; ++r) {
#pragma unroll
        for (int o = 8; o >= 1; o >>= 1) sm[r] += __shfl_xor(sm[r], o, 64);
        sm[r] = 1.0f / sm[r];
    }

    // ---- store: O row = quad*4+r, col = j*16+l16 ----
#pragma unroll
    for (int j = 0; j < 4; ++j)
#pragma unroll
        for (int r = 0; r < 4; ++r) {
            const int t = trow + r;
            attnb[((size_t)(nB * SEQ + t)) * D_MODEL + h * 64 + j * 16 + l16] =
                f2bf(oacc[j][r] * sm[r]);
        }
}

// ---------------------------------------------------------------------------
extern "C" void kernel_launch(void* const* d_in, const int* in_sizes, int n_in,
                              void* d_out, int out_size, void* d_ws, size_t ws_size,
                              hipStream_t stream)
{
    (void)in_sizes; (void)n_in; (void)out_size; (void)ws_size;
    const float* x     = (const float*)d_in[0];
    const float* w_qkv = (const float*)d_in[1];
    const float* w_out = (const float*)d_in[2];
    const float* b_out = (const float*)d_in[3];
    float* out = (float*)d_out;

    const int M = BATCH * SEQ;                 // 4096

    // ws layout (ushorts), 41.9 MB total:
    //   qb | kb | vbT | wob | xb | wqb   (attnb reuses xb after QKV GEMM)
    unsigned short* qb  = (unsigned short*)d_ws;
    unsigned short* kb  = qb  + (size_t)4194304;
    unsigned short* vbT = kb  + (size_t)4194304;
    unsigned short* wob = vbT + (size_t)4194304;
    unsigned short* xb  = wob + (size_t)1048576;
    unsigned short* wqb = xb  + (size_t)4194304;
    unsigned short* attnb = xb;

    dim3 blk(256);

    // 0) fp32 -> bf16 conversions (single launch)
    cvt_all<<<dim3((NX_ELEM + NW_ELEM + NO_ELEM) / 4 / 256), blk, 0, stream>>>(
        x, w_qkv, w_out, xb, wqb, wob);

    // 1) fused QKV projection + RoPE -> qb,kb [n,h,t,64], vbT [n,h,64,t] (bf16)
    gemm_qkv<<<dim3(3 * D_MODEL / 128, M / 128), blk, 0, stream>>>(
        xb, wqb, qb, kb, vbT, M, 3 * D_MODEL, D_MODEL);

    // 2) banded MFMA attention (async-staged V) -> attnb
    attn_mfma<<<dim3(SEQ / 64, N_HEADS, BATCH), blk, 0, stream>>>(qb, kb, vbT, attnb);

    // 3) out = attn @ w_out^T + b_out   (BM=64: grid 8 x 64 = 512 blocks)
    gemm_out<<<dim3(D_MODEL / 128, M / 64), blk, 0, stream>>>(
        attnb, wob, b_out, out, M, D_MODEL, D_MODEL);
}